// Round 5
// baseline (207.328 us; speedup 1.0000x reference)
//
#include <hip/hip_runtime.h>

typedef __attribute__((ext_vector_type(8))) short short8v;
typedef __attribute__((ext_vector_type(4))) short short4v;
typedef __attribute__((ext_vector_type(4))) float floatx4;
typedef __attribute__((ext_vector_type(16))) float f32x16;
typedef __attribute__((ext_vector_type(4))) unsigned uint4v;
typedef __attribute__((ext_vector_type(2))) unsigned uint2v;

#define S_LEN 1024
#define DMODEL 1024
#define NH 16
#define DK 64
#define NB_TAB 2047  // rel = k - q in [-1023, 1023]
#define L2E 1.4426950408889634f

__device__ __forceinline__ short f2bf(float f) {
  unsigned u = __builtin_bit_cast(unsigned, f);
  u += 0x7fffu + ((u >> 16) & 1u);  // RNE
  return (short)(u >> 16);
}

__device__ __forceinline__ float b2f(short s) {
  return __builtin_bit_cast(float, ((unsigned)(unsigned short)s) << 16);
}

__device__ __forceinline__ unsigned cvtpk(float lo, float hi) {
  unsigned r;
  asm("v_cvt_pk_bf16_f32 %0, %1, %2" : "=v"(r) : "v"(lo), "v"(hi));
  return r;
}

__device__ __forceinline__ void pswap(unsigned& x, unsigned& y) {
  asm volatile("v_permlane32_swap_b32 %0, %1" : "+v"(x), "+v"(y));
}

__device__ __forceinline__ float exp2a(float x) {  // 2^x via native v_exp_f32
  float r;
  asm("v_exp_f32 %0, %1" : "=v"(r) : "v"(x));
  return r;
}

__device__ __forceinline__ void load16(const void* g, void* l) {
  __builtin_amdgcn_global_load_lds((const __attribute__((address_space(1))) unsigned*)g,
                                   (__attribute__((address_space(3))) unsigned*)l, 16, 0, 0);
}

// 4 weight transposes in one launch: z<3 -> wT + z*1M (wq,wk,wv), z=3 -> wTo (wo)
__global__ __launch_bounds__(256) void transpose4_k(const float* __restrict__ wq,
                                                    const float* __restrict__ wk,
                                                    const float* __restrict__ wv,
                                                    const float* __restrict__ wo,
                                                    short* __restrict__ wT,
                                                    short* __restrict__ wTo) {
  __shared__ float t[32][33];
  int z = blockIdx.z;
  const float* in = z == 0 ? wq : (z == 1 ? wk : (z == 2 ? wv : wo));
  short* out = z < 3 ? wT + (size_t)z * 1024 * 1024 : wTo;
  int tx = threadIdx.x, ty = threadIdx.y;
  int bx = blockIdx.x * 32, by = blockIdx.y * 32;
#pragma unroll
  for (int i = ty; i < 32; i += 8) t[i][tx] = in[(size_t)(by + i) * DMODEL + bx + tx];
  __syncthreads();
#pragma unroll
  for (int i = ty; i < 32; i += 8) out[(size_t)(bx + i) * DMODEL + by + tx] = f2bf(t[tx][i]);
}

// fp32 -> bf16 bulk convert, 8 elems/thread
__global__ __launch_bounds__(256) void cvt_k(const float* __restrict__ in,
                                             short* __restrict__ out) {
  size_t i = ((size_t)blockIdx.x * 256 + threadIdx.x) * 8;
  const floatx4* p = (const floatx4*)(in + i);
  floatx4 a = p[0], b = p[1];
  short8v o;
#pragma unroll
  for (int j = 0; j < 4; ++j) {
    o[j] = f2bf(a[j]);
    o[4 + j] = f2bf(b[j]);
  }
  *(short8v*)(out + i) = o;
}

// 4-replicated T5 bias table, *log2e, bf16: B4[h][idx][j] = bias(idx+j-1023), idx in [0,2048)
__global__ __launch_bounds__(256) void bias4_k(const float* __restrict__ rel_bias,
                                               short* __restrict__ B4) {
  int gid = blockIdx.x * 256 + threadIdx.x;  // 16*2048
  int h = gid >> 11, idx = gid & 2047;
  short4v o;
#pragma unroll
  for (int j = 0; j < 4; ++j) {
    int ri = idx + j;
    if (ri > 2046) ri = 2046;
    int rel = ri - 1023;  // k - q
    int bucket = (rel > 0) ? 16 : 0;
    int r = rel < 0 ? -rel : rel;
    int bb;
    if (r < 8) {
      bb = r;
    } else {
      float lf = logf((float)r * 0.125f) * (8.0f / 2.772588722239781f);
      bb = 8 + (int)lf;
      if (bb > 15) bb = 15;
    }
    bucket += bb;
    o[j] = f2bf(rel_bias[bucket * NH + h] * L2E);
  }
  *(short4v*)(B4 + (size_t)gid * 4) = o;
}

// mask fp32 [q][kv] -> bf16 * log2e, stored pre-swizzled for attn LDS staging:
// within each 128B (64-kv) row segment: 16B slot s' = s ^ (q&7); 8B halves swapped if q&8.
__global__ __launch_bounds__(256) void masksw_k(const float* __restrict__ mask,
                                                short* __restrict__ Msw) {
  int gid = blockIdx.x * 256 + threadIdx.x;  // 1024*128 threads, 8 kv each
  int q = gid >> 7, kvg = gid & 127;
  int kv = kvg * 8;
  floatx4 m0 = *(const floatx4*)(mask + (size_t)q * 1024 + kv);
  floatx4 m1 = *(const floatx4*)(mask + (size_t)q * 1024 + kv + 4);
  unsigned u0 = cvtpk(m0[0] * L2E, m0[1] * L2E), u1 = cvtpk(m0[2] * L2E, m0[3] * L2E);
  unsigned u2 = cvtpk(m1[0] * L2E, m1[1] * L2E), u3 = cvtpk(m1[2] * L2E, m1[3] * L2E);
  uint4v uu;
  if (q & 8) {
    uu[0] = u2; uu[1] = u3; uu[2] = u0; uu[3] = u1;
  } else {
    uu[0] = u0; uu[1] = u1; uu[2] = u2; uu[3] = u3;
  }
  int seg = kvg >> 3, sslot = (kvg & 7) ^ (q & 7);
  *(uint4v*)(Msw + (size_t)q * 1024 + seg * 64 + sslot * 8) = uu;
}

// V[bh][s][d] -> Vt[bh][d][s], bf16. grid (4 s-chunks, 64 bh), block 256.
__global__ __launch_bounds__(256) void vtrans_k(const short* __restrict__ V,
                                                short* __restrict__ Vt) {
  __shared__ short t[64 * 256];
  int tid = threadIdx.x;
  int s0 = blockIdx.x * 256;
  int bh = blockIdx.y;
#pragma unroll
  for (int i = 0; i < 8; ++i) {
    int s = i * 32 + (tid >> 3);
    int slot = tid & 7;
    short8v vv = *(const short8v*)&V[(((size_t)bh * S_LEN) + s0 + s) * DK + slot * 8];
#pragma unroll
    for (int j = 0; j < 8; ++j) {
      int d = slot * 8 + j;
      *(short*)((char*)t + d * 512 + ((s * 2) ^ (((d >> 3) & 7) << 4))) = vv[j];
    }
  }
  __syncthreads();
#pragma unroll
  for (int i = 0; i < 8; ++i) {
    int d = i * 8 + (tid >> 5);
    int sl = tid & 31;
    short8v vv = *(const short8v*)((char*)t + d * 512 + ((sl * 16) ^ (((d >> 3) & 7) << 4)));
    *(short8v*)&Vt[(((size_t)bh * DK) + d) * S_LEN + s0 + sl * 8] = vv;
  }
}

// GEMM C[M,N] = A[M,K(=1024)] * BT[N,K]^T, bf16 in, fp32 acc.
// EPI 0: scatter bf16 to Q/K/V per-head (Q scaled by log2e); EPI 1: fp32 C.
template <int EPI>
__global__ __launch_bounds__(256) void gemm2_k(const short* __restrict__ A,
                                               const short* __restrict__ BT,
                                               short* __restrict__ Qo, short* __restrict__ Ko,
                                               short* __restrict__ Vo, float* __restrict__ Fo) {
  constexpr int K = DMODEL;
  __shared__ short lA[128 * 64];
  __shared__ short lB[128 * 64];
  int tid = threadIdx.x;
  int lane = tid & 63, wid = tid >> 6;
  int lane16 = lane & 15, kl = lane >> 4;
  int bm = blockIdx.y * 128, bn = blockIdx.x * 128;
  int wm = (wid & 1) * 64, wn = (wid >> 1) * 64;
  floatx4 acc[4][4] = {};

  const char* gA[4];
  const char* gB[4];
  int slot = lane & 7;
#pragma unroll
  for (int it = 0; it < 4; ++it) {
    int row = it * 32 + wid * 8 + (lane >> 3);
    int sw = (slot * 16) ^ ((row & 7) << 4);
    gA[it] = (const char*)A + ((size_t)(bm + row) * K) * 2 + sw;
    gB[it] = (const char*)BT + ((size_t)(bn + row) * K) * 2 + sw;
  }

  for (int k0 = 0; k0 < K; k0 += 64) {
    __syncthreads();
#pragma unroll
    for (int it = 0; it < 4; ++it) {
      char* la = (char*)lA + (it * 32 + wid * 8) * 128;
      char* lb = (char*)lB + (it * 32 + wid * 8) * 128;
      load16(gA[it] + k0 * 2, la);
      load16(gB[it] + k0 * 2, lb);
    }
    __syncthreads();
#pragma unroll
    for (int kc = 0; kc < 2; ++kc) {
      short8v af[4], bf[4];
#pragma unroll
      for (int mt = 0; mt < 4; ++mt) {
        int row = wm + mt * 16 + lane16;
        af[mt] = *(const short8v*)((char*)lA + row * 128 +
                                   ((kc * 64 + kl * 16) ^ ((row & 7) << 4)));
      }
#pragma unroll
      for (int nt = 0; nt < 4; ++nt) {
        int row = wn + nt * 16 + lane16;
        bf[nt] = *(const short8v*)((char*)lB + row * 128 +
                                   ((kc * 64 + kl * 16) ^ ((row & 7) << 4)));
      }
#pragma unroll
      for (int mt = 0; mt < 4; ++mt)
#pragma unroll
        for (int nt = 0; nt < 4; ++nt)
          acc[mt][nt] =
              __builtin_amdgcn_mfma_f32_16x16x32_bf16(af[mt], bf[nt], acc[mt][nt], 0, 0, 0);
    }
  }
  if constexpr (EPI == 0) {
    int which = bn >> 10;
    int gcb = bn & 1023;
    short* dst = which == 0 ? Qo : (which == 1 ? Ko : Vo);
    float scl = which == 0 ? L2E : 1.0f;  // fold log2e into Q for exp2-domain softmax
#pragma unroll
    for (int mt = 0; mt < 4; ++mt)
#pragma unroll
      for (int nt = 0; nt < 4; ++nt)
#pragma unroll
        for (int r = 0; r < 4; ++r) {
          int gr = bm + wm + mt * 16 + kl * 4 + r;
          int gc = gcb + wn + nt * 16 + lane16;
          int hh = gc >> 6, d = gc & 63;
          int bb = gr >> 10, s = gr & 1023;
          dst[(size_t)((bb * 16 + hh) * 1024 + s) * 64 + d] = f2bf(acc[mt][nt][r] * scl);
        }
  } else {
#pragma unroll
    for (int mt = 0; mt < 4; ++mt)
#pragma unroll
      for (int nt = 0; nt < 4; ++nt)
#pragma unroll
        for (int r = 0; r < 4; ++r) {
          int gr = bm + wm + mt * 16 + kl * 4 + r;
          int gc = bn + wn + nt * 16 + lane16;
          Fo[(size_t)gr * DMODEL + gc] = acc[mt][nt][r];
        }
  }
}

// Flash attention, exp2-domain. 4 waves x 32 q = 128 q/block, grid (8, 64).
// Swapped QK^T (32x32x16): q on lane axis. Mask tile staged (pre-swizzled bf16),
// bias via 4-replicated LDS table (single ds_read_b64 per 4 kv). 1 barrier/iter.
__global__ __launch_bounds__(256) void attn32_k(const short* __restrict__ Q,
                                                const short* __restrict__ Kg,
                                                const short* __restrict__ Vt,
                                                const short* __restrict__ Msw,
                                                const short* __restrict__ B4g,
                                                short* __restrict__ O) {
  __shared__ short lK[2][64 * 64];   // [buf][kv][d], 16B-slot swizzled
  __shared__ short lV[2][64 * 64];   // [buf][d][kv], 16B-slot swizzled
  __shared__ short lM[2][128 * 64];  // [buf][q][kv] mask*log2e, swizzled (baked in Msw)
  __shared__ short lB4[2048 * 4];    // bias4 for this head
  int tid = threadIdx.x;
  int lane = tid & 63, wid = tid >> 6;
  int l31 = lane & 31, L = lane >> 5;
  int qt = blockIdx.x, bh = blockIdx.y;
  int h = bh & 15, b = bh >> 4;
  int q = qt * 128 + wid * 32 + l31;
  int q_r = wid * 32 + l31;

  // K/V staging pointers (inverse-swizzled source, linear LDS dest)
  const char* gK[2];
  const char* gV[2];
  int ldst[2];
  {
    int slot = lane & 7;
#pragma unroll
    for (int i = 0; i < 2; ++i) {
      int row = i * 32 + wid * 8 + (lane >> 3);
      int ss = slot ^ ((row ^ (row >> 3)) & 7);
      gK[i] = (const char*)Kg + ((size_t)(bh * S_LEN + row) * DK + ss * 8) * 2;
      gV[i] = (const char*)Vt + ((size_t)(bh * DK + row) * S_LEN + ss * 8) * 2;
      ldst[i] = (i * 32 + wid * 8) * 128;
    }
  }
  // mask staging pointers (source already swizzled; linear copy)
  const char* gM[4];
  int ldstM[4];
#pragma unroll
  for (int c = 0; c < 4; ++c) {
    int row = c * 32 + wid * 8 + (lane >> 3);
    gM[c] = (const char*)Msw + ((size_t)(qt * 128 + row) * 1024) * 2 + (lane & 7) * 16;
    ldstM[c] = c * 4096 + wid * 1024;
  }
  // prologue: stage tile 0
#pragma unroll
  for (int i = 0; i < 2; ++i) {
    load16(gK[i], (char*)lK[0] + ldst[i]);
    load16(gV[i], (char*)lV[0] + ldst[i]);
  }
#pragma unroll
  for (int c = 0; c < 4; ++c) load16(gM[c], (char*)lM[0] + ldstM[c]);
  // bias table fill (16 KB, coalesced)
  {
    const short8v* src = (const short8v*)(B4g + (size_t)h * 8192);
    short8v* dst = (short8v*)lB4;
    for (int i = tid; i < 1024; i += 256) dst[i] = src[i];
  }
  // Q B-frags: col=lane&31=q, k = ds*16 + L*8 + j
  const short8v* qp = (const short8v*)(Q + ((size_t)bh * S_LEN + q) * DK);
  short8v qf[4];
#pragma unroll
  for (int ds = 0; ds < 4; ++ds) qf[ds] = qp[ds * 2 + L];

  f32x16 ot[2] = {};  // O^T: rows d = dt*32+(reg&3)+8*(reg>>2)+4L, col q
  float m_ = -1e30f, l_ = 0.0f;
  int swq = ((q_r & 7) << 4) | (q_r & 8);
  __syncthreads();

  for (int it = 0; it < 16; ++it) {
    int kv0 = it * 64;
    int cur = it & 1;
    // stage next tile into other buffers
    if (it < 15) {
#pragma unroll
      for (int i = 0; i < 2; ++i) {
        load16(gK[i] + (size_t)(kv0 + 64) * 128, (char*)lK[cur ^ 1] + ldst[i]);
        load16(gV[i] + (size_t)(kv0 + 64) * 2, (char*)lV[cur ^ 1] + ldst[i]);
      }
#pragma unroll
      for (int c = 0; c < 4; ++c)
        load16(gM[c] + (size_t)(kv0 + 64) * 2, (char*)lM[cur ^ 1] + ldstM[c]);
    }
    // mask + bias LDS reads (independent of QK chain; overlap MFMA)
    short4v mb[2][4], bb[2][4];
#pragma unroll
    for (int hh = 0; hh < 2; ++hh)
#pragma unroll
      for (int g = 0; g < 4; ++g) {
        mb[hh][g] = *(const short4v*)((const char*)lM[cur] + q_r * 128 +
                                      ((hh * 64 + 16 * g + 8 * L) ^ swq));
        bb[hh][g] =
            *(const short4v*)(lB4 + (size_t)(kv0 + hh * 32 + 8 * g + 4 * L - q + 1023) * 4);
      }
    // S^T = K * Q^T
    f32x16 sA[2];
#pragma unroll
    for (int hh = 0; hh < 2; ++hh) {
      f32x16 acc = {};
#pragma unroll
      for (int ds = 0; ds < 4; ++ds) {
        int row = hh * 32 + l31;
        int sw = ((row ^ (row >> 3)) & 7) << 4;
        short8v kf =
            *(const short8v*)((const char*)lK[cur] + row * 128 + ((ds * 32 + L * 16) ^ sw));
        acc = __builtin_amdgcn_mfma_f32_32x32x16_bf16(kf, qf[ds], acc, 0, 0, 0);
      }
      sA[hh] = acc;
    }
    // scores (log2 domain): s = qk*log2e + (mask+bias)*log2e
    float p[2][16];
#pragma unroll
    for (int hh = 0; hh < 2; ++hh)
#pragma unroll
      for (int g = 0; g < 4; ++g)
#pragma unroll
        for (int r3 = 0; r3 < 4; ++r3)
          p[hh][4 * g + r3] = sA[hh][4 * g + r3] + b2f(mb[hh][g][r3]) + b2f(bb[hh][g][r3]);
    // online softmax, lane-local q; one cross-half exchange
    float mx0 = p[0][0], mx1 = p[0][1], mx2 = p[0][2], mx3 = p[0][3];
#pragma unroll
    for (int hh = 0; hh < 2; ++hh)
#pragma unroll
      for (int r = (hh == 0 ? 4 : 0); r < 16; r += 4) {
        mx0 = fmaxf(mx0, p[hh][r]);
        mx1 = fmaxf(mx1, p[hh][r + 1]);
        mx2 = fmaxf(mx2, p[hh][r + 2]);
        mx3 = fmaxf(mx3, p[hh][r + 3]);
      }
    float pmax = fmaxf(fmaxf(mx0, mx1), fmaxf(mx2, mx3));
    pmax = fmaxf(pmax, __shfl_xor(pmax, 32));
    if (__any(pmax > m_ + 11.5f)) {  // defer-max (e^8 bound in log2 domain)
      float mn = fmaxf(m_, pmax);
      float al = exp2a(m_ - mn);
      m_ = mn;
      l_ *= al;
#pragma unroll
      for (int dt = 0; dt < 2; ++dt) ot[dt] *= al;
    }
    float s0 = 0.0f, s1 = 0.0f, s2 = 0.0f, s3 = 0.0f;
#pragma unroll
    for (int hh = 0; hh < 2; ++hh)
#pragma unroll
      for (int g = 0; g < 4; ++g) {
        float e0 = exp2a(p[hh][4 * g + 0] - m_);
        float e1 = exp2a(p[hh][4 * g + 1] - m_);
        float e2 = exp2a(p[hh][4 * g + 2] - m_);
        float e3 = exp2a(p[hh][4 * g + 3] - m_);
        p[hh][4 * g + 0] = e0;
        p[hh][4 * g + 1] = e1;
        p[hh][4 * g + 2] = e2;
        p[hh][4 * g + 3] = e3;
        s0 += e0;
        s1 += e1;
        s2 += e2;
        s3 += e3;
      }
    float s = (s0 + s1) + (s2 + s3);
    s += __shfl_xor(s, 32);
    l_ += s;
    // P^T B-frags via cvt_pk + permlane32_swap, then O^T += V^T * P^T
#pragma unroll
    for (int ks = 0; ks < 4; ++ks) {
      const int hh = ks >> 1, bq = (ks & 1) * 8;
      unsigned A0 = cvtpk(p[hh][bq + 0], p[hh][bq + 1]);
      unsigned A1 = cvtpk(p[hh][bq + 2], p[hh][bq + 3]);
      unsigned B0 = cvtpk(p[hh][bq + 4], p[hh][bq + 5]);
      unsigned B1 = cvtpk(p[hh][bq + 6], p[hh][bq + 7]);
      pswap(A0, B0);
      pswap(A1, B1);
      uint4v uu = {A0, A1, B0, B1};
      short8v pf = __builtin_bit_cast(short8v, uu);
#pragma unroll
      for (int dt = 0; dt < 2; ++dt) {
        int row = dt * 32 + l31;
        int sw = ((row ^ (row >> 3)) & 7) << 4;
        short8v vf =
            *(const short8v*)((const char*)lV[cur] + row * 128 + ((ks * 32 + L * 16) ^ sw));
        ot[dt] = __builtin_amdgcn_mfma_f32_32x32x16_bf16(vf, pf, ot[dt], 0, 0, 0);
      }
    }
    __syncthreads();  // staged next-tile done (vmcnt drain) + all reads of cur done
  }
  // epilogue: O = O^T / l, write bf16 [b*S+q][h*64+d]
  float inv = 1.0f / l_;
  short* ob = O + ((size_t)(b * S_LEN + q)) * DMODEL + h * 64;
#pragma unroll
  for (int dt = 0; dt < 2; ++dt)
#pragma unroll
    for (int g = 0; g < 4; ++g) {
      int d0 = dt * 32 + 8 * g + 4 * L;
      uint2v w = {cvtpk(ot[dt][4 * g + 0] * inv, ot[dt][4 * g + 1] * inv),
                  cvtpk(ot[dt][4 * g + 2] * inv, ot[dt][4 * g + 3] * inv)};
      *(uint2v*)(ob + d0) = w;
    }
}

extern "C" void kernel_launch(void* const* d_in, const int* in_sizes, int n_in, void* d_out,
                              int out_size, void* d_ws, size_t ws_size, hipStream_t stream) {
  (void)in_sizes;
  (void)n_in;
  (void)out_size;
  (void)ws_size;
  const float* hs = (const float*)d_in[0];
  const float* mask = (const float*)d_in[1];
  const float* wq = (const float*)d_in[2];
  const float* wk = (const float*)d_in[3];
  const float* wv = (const float*)d_in[4];
  const float* wo = (const float*)d_in[5];
  const float* relb = (const float*)d_in[6];
  float* out = (float*)d_out;
  char* ws = (char*)d_ws;
  const size_t MB = 1024 * 1024;
  short* wT = (short*)(ws);              // [3072][1024] bf16
  short* wTo = (short*)(ws + 6 * MB);    // [1024][1024] bf16
  short* Ab = (short*)(ws + 8 * MB);     // [4096][1024] bf16 (hs); reused as Ob
  short* Qb = (short*)(ws + 16 * MB);    // [64][1024][64] bf16
  short* Kb = (short*)(ws + 24 * MB);
  short* Vb = (short*)(ws + 32 * MB);
  short* Vtb = (short*)(ws + 40 * MB);   // [64][64][1024] bf16
  short* B4 = (short*)(ws + 48 * MB);    // [16][2048][4] bf16 (256 KB)
  short* Msw = (short*)(ws + 49 * MB);   // [1024][1024] bf16 swizzled (2 MB)
  short* Ob = Ab;

  transpose4_k<<<dim3(32, 32, 4), dim3(32, 8), 0, stream>>>(wq, wk, wv, wo, wT, wTo);
  bias4_k<<<16 * 2048 / 256, 256, 0, stream>>>(relb, B4);
  masksw_k<<<1024 * 128 / 256, 256, 0, stream>>>(mask, Msw);
  cvt_k<<<4096 * 1024 / 8 / 256, 256, 0, stream>>>(hs, Ab);
  gemm2_k<0><<<dim3(3072 / 128, 4096 / 128), 256, 0, stream>>>(Ab, wT, Qb, Kb, Vb, nullptr);
  vtrans_k<<<dim3(4, 64), 256, 0, stream>>>(Vb, Vtb);
  attn32_k<<<dim3(8, 64), 256, 0, stream>>>(Qb, Kb, Vtb, Msw, B4, Ob);
  gemm2_k<1><<<dim3(1024 / 128, 4096 / 128), 256, 0, stream>>>(Ob, wTo, nullptr, nullptr, nullptr,
                                                               out);
}

// Round 6
// 195.726 us; speedup vs baseline: 1.0593x; 1.0593x over previous
//
#include <hip/hip_runtime.h>

typedef __attribute__((ext_vector_type(8))) short short8v;
typedef __attribute__((ext_vector_type(4))) short short4v;
typedef __attribute__((ext_vector_type(4))) float floatx4;
typedef __attribute__((ext_vector_type(16))) float f32x16;
typedef __attribute__((ext_vector_type(4))) unsigned uint4v;
typedef __attribute__((ext_vector_type(2))) unsigned uint2v;

#define S_LEN 1024
#define DMODEL 1024
#define NH 16
#define DK 64
#define NB_TAB 2047  // rel = k - q in [-1023, 1023]
#define L2E 1.4426950408889634f
#define FMAX_C 16.0f  // fixed softmax offset (log2 domain), folded into mask table

__device__ __forceinline__ short f2bf(float f) {
  unsigned u = __builtin_bit_cast(unsigned, f);
  u += 0x7fffu + ((u >> 16) & 1u);  // RNE
  return (short)(u >> 16);
}

__device__ __forceinline__ float b2f(short s) {
  return __builtin_bit_cast(float, ((unsigned)(unsigned short)s) << 16);
}

__device__ __forceinline__ unsigned cvtpk(float lo, float hi) {
  unsigned r;
  asm("v_cvt_pk_bf16_f32 %0, %1, %2" : "=v"(r) : "v"(lo), "v"(hi));
  return r;
}

__device__ __forceinline__ void pswap(unsigned& x, unsigned& y) {
  asm volatile("v_permlane32_swap_b32 %0, %1" : "+v"(x), "+v"(y));
}

__device__ __forceinline__ float exp2a(float x) {  // 2^x via native v_exp_f32
  float r;
  asm("v_exp_f32 %0, %1" : "=v"(r) : "v"(x));
  return r;
}

__device__ __forceinline__ void load16(const void* g, void* l) {
  __builtin_amdgcn_global_load_lds((const __attribute__((address_space(1))) unsigned*)g,
                                   (__attribute__((address_space(3))) unsigned*)l, 16, 0, 0);
}

// 4 weight transposes in one launch: z<3 -> wT + z*1M (wq,wk,wv), z=3 -> wTo (wo)
__global__ __launch_bounds__(256) void transpose4_k(const float* __restrict__ wq,
                                                    const float* __restrict__ wk,
                                                    const float* __restrict__ wv,
                                                    const float* __restrict__ wo,
                                                    short* __restrict__ wT,
                                                    short* __restrict__ wTo) {
  __shared__ float t[32][33];
  int z = blockIdx.z;
  const float* in = z == 0 ? wq : (z == 1 ? wk : (z == 2 ? wv : wo));
  short* out = z < 3 ? wT + (size_t)z * 1024 * 1024 : wTo;
  int tx = threadIdx.x, ty = threadIdx.y;
  int bx = blockIdx.x * 32, by = blockIdx.y * 32;
#pragma unroll
  for (int i = ty; i < 32; i += 8) t[i][tx] = in[(size_t)(by + i) * DMODEL + bx + tx];
  __syncthreads();
#pragma unroll
  for (int i = ty; i < 32; i += 8) out[(size_t)(bx + i) * DMODEL + by + tx] = f2bf(t[tx][i]);
}

// fp32 -> bf16 bulk convert, 8 elems/thread
__global__ __launch_bounds__(256) void cvt_k(const float* __restrict__ in,
                                             short* __restrict__ out) {
  size_t i = ((size_t)blockIdx.x * 256 + threadIdx.x) * 8;
  const floatx4* p = (const floatx4*)(in + i);
  floatx4 a = p[0], b = p[1];
  short8v o;
#pragma unroll
  for (int j = 0; j < 4; ++j) {
    o[j] = f2bf(a[j]);
    o[4 + j] = f2bf(b[j]);
  }
  *(short8v*)(out + i) = o;
}

// 4-replicated T5 bias table, *log2e, bf16: B4[h][idx][j] = bias(idx+j-1023), idx in [0,2048)
__global__ __launch_bounds__(256) void bias4_k(const float* __restrict__ rel_bias,
                                               short* __restrict__ B4) {
  int gid = blockIdx.x * 256 + threadIdx.x;  // 16*2048
  int h = gid >> 11, idx = gid & 2047;
  short4v o;
#pragma unroll
  for (int j = 0; j < 4; ++j) {
    int ri = idx + j;
    if (ri > 2046) ri = 2046;
    int rel = ri - 1023;  // k - q
    int bucket = (rel > 0) ? 16 : 0;
    int r = rel < 0 ? -rel : rel;
    int bb;
    if (r < 8) {
      bb = r;
    } else {
      float lf = logf((float)r * 0.125f) * (8.0f / 2.772588722239781f);
      bb = 8 + (int)lf;
      if (bb > 15) bb = 15;
    }
    bucket += bb;
    o[j] = f2bf(rel_bias[bucket * NH + h] * L2E);
  }
  *(short4v*)(B4 + (size_t)gid * 4) = o;
}

// mask fp32 [q][kv] -> bf16 (mask*log2e - FMAX_C), stored pre-swizzled for attn LDS staging:
// within each 128B (64-kv) row segment: 16B slot s' = s ^ (q&7); 8B halves swapped if q&8.
__global__ __launch_bounds__(256) void masksw_k(const float* __restrict__ mask,
                                                short* __restrict__ Msw) {
  int gid = blockIdx.x * 256 + threadIdx.x;  // 1024*128 threads, 8 kv each
  int q = gid >> 7, kvg = gid & 127;
  int kv = kvg * 8;
  floatx4 m0 = *(const floatx4*)(mask + (size_t)q * 1024 + kv);
  floatx4 m1 = *(const floatx4*)(mask + (size_t)q * 1024 + kv + 4);
  unsigned u0 = cvtpk(m0[0] * L2E - FMAX_C, m0[1] * L2E - FMAX_C);
  unsigned u1 = cvtpk(m0[2] * L2E - FMAX_C, m0[3] * L2E - FMAX_C);
  unsigned u2 = cvtpk(m1[0] * L2E - FMAX_C, m1[1] * L2E - FMAX_C);
  unsigned u3 = cvtpk(m1[2] * L2E - FMAX_C, m1[3] * L2E - FMAX_C);
  uint4v uu;
  if (q & 8) {
    uu[0] = u2; uu[1] = u3; uu[2] = u0; uu[3] = u1;
  } else {
    uu[0] = u0; uu[1] = u1; uu[2] = u2; uu[3] = u3;
  }
  int seg = kvg >> 3, sslot = (kvg & 7) ^ (q & 7);
  *(uint4v*)(Msw + (size_t)q * 1024 + seg * 64 + sslot * 8) = uu;
}

// V[bh][s][d] -> Vt[bh][d][s], bf16. grid (4 s-chunks, 64 bh), block 256.
__global__ __launch_bounds__(256) void vtrans_k(const short* __restrict__ V,
                                                short* __restrict__ Vt) {
  __shared__ short t[64 * 256];
  int tid = threadIdx.x;
  int s0 = blockIdx.x * 256;
  int bh = blockIdx.y;
#pragma unroll
  for (int i = 0; i < 8; ++i) {
    int s = i * 32 + (tid >> 3);
    int slot = tid & 7;
    short8v vv = *(const short8v*)&V[(((size_t)bh * S_LEN) + s0 + s) * DK + slot * 8];
#pragma unroll
    for (int j = 0; j < 8; ++j) {
      int d = slot * 8 + j;
      *(short*)((char*)t + d * 512 + ((s * 2) ^ (((d >> 3) & 7) << 4))) = vv[j];
    }
  }
  __syncthreads();
#pragma unroll
  for (int i = 0; i < 8; ++i) {
    int d = i * 8 + (tid >> 5);
    int sl = tid & 31;
    short8v vv = *(const short8v*)((char*)t + d * 512 + ((sl * 16) ^ (((d >> 3) & 7) << 4)));
    *(short8v*)&Vt[(((size_t)bh * DK) + d) * S_LEN + s0 + sl * 8] = vv;
  }
}

// GEMM C[M,N] = A[M,K(=1024)] * BT[N,K]^T, bf16 in, fp32 acc. 1D grid with
// XCD-chunked + group-M(8) block swizzle for L2 locality (T1).
// EPI 0: scatter bf16 to Q/K/V per-head (Q scaled by log2e); EPI 1: fp32 C.
template <int EPI, int NBN, int NBM>
__global__ __launch_bounds__(256) void gemm2_k(const short* __restrict__ A,
                                               const short* __restrict__ BT,
                                               short* __restrict__ Qo, short* __restrict__ Ko,
                                               short* __restrict__ Vo, float* __restrict__ Fo) {
  constexpr int K = DMODEL;
  constexpr int TOTAL = NBN * NBM;
  constexpr int CHUNK = TOTAL / 8;
  __shared__ short lA[128 * 64];
  __shared__ short lB[128 * 64];
  int tid = threadIdx.x;
  int lane = tid & 63, wid = tid >> 6;
  int lane16 = lane & 15, kl = lane >> 4;
  // block swizzle: XCD chunking then group-M(8)
  int bid = blockIdx.x;
  int lb = (bid & 7) * CHUNK + (bid >> 3);
  int g = lb / (8 * NBN), r = lb % (8 * NBN);
  int bm = (g * 8 + (r & 7)) * 128, bn = (r >> 3) * 128;
  int wm = (wid & 1) * 64, wn = (wid >> 1) * 64;
  floatx4 acc[4][4] = {};

  const char* gA[4];
  const char* gB[4];
  int slot = lane & 7;
#pragma unroll
  for (int it = 0; it < 4; ++it) {
    int row = it * 32 + wid * 8 + (lane >> 3);
    int sw = (slot * 16) ^ ((row & 7) << 4);
    gA[it] = (const char*)A + ((size_t)(bm + row) * K) * 2 + sw;
    gB[it] = (const char*)BT + ((size_t)(bn + row) * K) * 2 + sw;
  }

  for (int k0 = 0; k0 < K; k0 += 64) {
    __syncthreads();
#pragma unroll
    for (int it = 0; it < 4; ++it) {
      char* la = (char*)lA + (it * 32 + wid * 8) * 128;
      char* lb2 = (char*)lB + (it * 32 + wid * 8) * 128;
      load16(gA[it] + k0 * 2, la);
      load16(gB[it] + k0 * 2, lb2);
    }
    __syncthreads();
#pragma unroll
    for (int kc = 0; kc < 2; ++kc) {
      short8v af[4], bf[4];
#pragma unroll
      for (int mt = 0; mt < 4; ++mt) {
        int row = wm + mt * 16 + lane16;
        af[mt] = *(const short8v*)((char*)lA + row * 128 +
                                   ((kc * 64 + kl * 16) ^ ((row & 7) << 4)));
      }
#pragma unroll
      for (int nt = 0; nt < 4; ++nt) {
        int row = wn + nt * 16 + lane16;
        bf[nt] = *(const short8v*)((char*)lB + row * 128 +
                                   ((kc * 64 + kl * 16) ^ ((row & 7) << 4)));
      }
#pragma unroll
      for (int mt = 0; mt < 4; ++mt)
#pragma unroll
        for (int nt = 0; nt < 4; ++nt)
          acc[mt][nt] =
              __builtin_amdgcn_mfma_f32_16x16x32_bf16(af[mt], bf[nt], acc[mt][nt], 0, 0, 0);
    }
  }
  if constexpr (EPI == 0) {
    int which = bn >> 10;
    int gcb = bn & 1023;
    short* dst = which == 0 ? Qo : (which == 1 ? Ko : Vo);
    float scl = which == 0 ? L2E : 1.0f;  // fold log2e into Q for exp2-domain softmax
#pragma unroll
    for (int mt = 0; mt < 4; ++mt)
#pragma unroll
      for (int nt = 0; nt < 4; ++nt)
#pragma unroll
        for (int r2 = 0; r2 < 4; ++r2) {
          int gr = bm + wm + mt * 16 + kl * 4 + r2;
          int gc = gcb + wn + nt * 16 + lane16;
          int hh = gc >> 6, d = gc & 63;
          int bb = gr >> 10, s = gr & 1023;
          dst[(size_t)((bb * 16 + hh) * 1024 + s) * 64 + d] = f2bf(acc[mt][nt][r2] * scl);
        }
  } else {
#pragma unroll
    for (int mt = 0; mt < 4; ++mt)
#pragma unroll
      for (int nt = 0; nt < 4; ++nt)
#pragma unroll
        for (int r2 = 0; r2 < 4; ++r2) {
          int gr = bm + wm + mt * 16 + kl * 4 + r2;
          int gc = bn + wn + nt * 16 + lane16;
          Fo[(size_t)gr * DMODEL + gc] = acc[mt][nt][r2];
        }
  }
}

// Flash attention, exp2-domain with FIXED max (logits bounded; -16 folded in mask
// table). 4 waves x 32 q = 128 q/block, 1D grid 512, XCD-chunked (8 bh per XCD).
// Swapped QK^T (32x32x16): q on lane axis. No online-max machinery; l combined
// across lane halves once at the end. 1 barrier/iter.
__global__ __launch_bounds__(256) void attn32_k(const short* __restrict__ Q,
                                                const short* __restrict__ Kg,
                                                const short* __restrict__ Vt,
                                                const short* __restrict__ Msw,
                                                const short* __restrict__ B4g,
                                                short* __restrict__ O) {
  __shared__ short lK[2][64 * 64];   // [buf][kv][d], 16B-slot swizzled
  __shared__ short lV[2][64 * 64];   // [buf][d][kv], 16B-slot swizzled
  __shared__ short lM[2][128 * 64];  // [buf][q][kv] mask*log2e - C, swizzled (in Msw)
  __shared__ short lB4[2048 * 4];    // bias4 for this head
  int tid = threadIdx.x;
  int lane = tid & 63, wid = tid >> 6;
  int l31 = lane & 31, L = lane >> 5;
  int bid = blockIdx.x;
  int lb = (bid & 7) * 64 + (bid >> 3);  // XCD chunk: 8 bh per XCD
  int bh = lb >> 3, qt = lb & 7;
  int h = bh & 15, b = bh >> 4;
  int q = qt * 128 + wid * 32 + l31;
  int q_r = wid * 32 + l31;

  // K/V staging pointers (inverse-swizzled source, linear LDS dest)
  const char* gK[2];
  const char* gV[2];
  int ldst[2];
  {
    int slot = lane & 7;
#pragma unroll
    for (int i = 0; i < 2; ++i) {
      int row = i * 32 + wid * 8 + (lane >> 3);
      int ss = slot ^ ((row ^ (row >> 3)) & 7);
      gK[i] = (const char*)Kg + ((size_t)(bh * S_LEN + row) * DK + ss * 8) * 2;
      gV[i] = (const char*)Vt + ((size_t)(bh * DK + row) * S_LEN + ss * 8) * 2;
      ldst[i] = (i * 32 + wid * 8) * 128;
    }
  }
  // mask staging pointers (source already swizzled; linear copy)
  const char* gM[4];
  int ldstM[4];
#pragma unroll
  for (int c = 0; c < 4; ++c) {
    int row = c * 32 + wid * 8 + (lane >> 3);
    gM[c] = (const char*)Msw + ((size_t)(qt * 128 + row) * 1024) * 2 + (lane & 7) * 16;
    ldstM[c] = c * 4096 + wid * 1024;
  }
  // prologue: stage tile 0
#pragma unroll
  for (int i = 0; i < 2; ++i) {
    load16(gK[i], (char*)lK[0] + ldst[i]);
    load16(gV[i], (char*)lV[0] + ldst[i]);
  }
#pragma unroll
  for (int c = 0; c < 4; ++c) load16(gM[c], (char*)lM[0] + ldstM[c]);
  // bias table fill (16 KB, coalesced)
  {
    const short8v* src = (const short8v*)(B4g + (size_t)h * 8192);
    short8v* dst = (short8v*)lB4;
    for (int i = tid; i < 1024; i += 256) dst[i] = src[i];
  }
  // Q B-frags: col=lane&31=q, k = ds*16 + L*8 + j
  const short8v* qp = (const short8v*)(Q + ((size_t)bh * S_LEN + q) * DK);
  short8v qf[4];
#pragma unroll
  for (int ds = 0; ds < 4; ++ds) qf[ds] = qp[ds * 2 + L];

  f32x16 ot[2] = {};  // O^T: rows d = dt*32+(reg&3)+8*(reg>>2)+4L, col q
  float l_ = 0.0f;
  int swq = ((q_r & 7) << 4) | (q_r & 8);
  __syncthreads();

  for (int it = 0; it < 16; ++it) {
    int kv0 = it * 64;
    int cur = it & 1;
    // stage next tile into other buffers
    if (it < 15) {
#pragma unroll
      for (int i = 0; i < 2; ++i) {
        load16(gK[i] + (size_t)(kv0 + 64) * 128, (char*)lK[cur ^ 1] + ldst[i]);
        load16(gV[i] + (size_t)(kv0 + 64) * 2, (char*)lV[cur ^ 1] + ldst[i]);
      }
#pragma unroll
      for (int c = 0; c < 4; ++c)
        load16(gM[c] + (size_t)(kv0 + 64) * 2, (char*)lM[cur ^ 1] + ldstM[c]);
    }
    // mask + bias LDS reads (independent of QK chain; overlap MFMA)
    short4v mb[2][4], bb[2][4];
#pragma unroll
    for (int hh = 0; hh < 2; ++hh)
#pragma unroll
      for (int g = 0; g < 4; ++g) {
        mb[hh][g] = *(const short4v*)((const char*)lM[cur] + q_r * 128 +
                                      ((hh * 64 + 16 * g + 8 * L) ^ swq));
        bb[hh][g] =
            *(const short4v*)(lB4 + (size_t)(kv0 + hh * 32 + 8 * g + 4 * L - q + 1023) * 4);
      }
    // S^T = K * Q^T
    f32x16 sA[2];
#pragma unroll
    for (int hh = 0; hh < 2; ++hh) {
      f32x16 acc = {};
#pragma unroll
      for (int ds = 0; ds < 4; ++ds) {
        int row = hh * 32 + l31;
        int sw = ((row ^ (row >> 3)) & 7) << 4;
        short8v kf =
            *(const short8v*)((const char*)lK[cur] + row * 128 + ((ds * 32 + L * 16) ^ sw));
        acc = __builtin_amdgcn_mfma_f32_32x32x16_bf16(kf, qf[ds], acc, 0, 0, 0);
      }
      sA[hh] = acc;
    }
    // p (log2 domain, already offset by -C via mask table), e = 2^p, sum into l_
    float p[2][16];
#pragma unroll
    for (int hh = 0; hh < 2; ++hh)
#pragma unroll
      for (int g = 0; g < 4; ++g)
#pragma unroll
        for (int r3 = 0; r3 < 4; ++r3)
          p[hh][4 * g + r3] = sA[hh][4 * g + r3] + b2f(mb[hh][g][r3]) + b2f(bb[hh][g][r3]);
    float s0 = 0.0f, s1 = 0.0f, s2 = 0.0f, s3 = 0.0f;
#pragma unroll
    for (int hh = 0; hh < 2; ++hh)
#pragma unroll
      for (int g = 0; g < 4; ++g) {
        float e0 = exp2a(p[hh][4 * g + 0]);
        float e1 = exp2a(p[hh][4 * g + 1]);
        float e2 = exp2a(p[hh][4 * g + 2]);
        float e3 = exp2a(p[hh][4 * g + 3]);
        p[hh][4 * g + 0] = e0;
        p[hh][4 * g + 1] = e1;
        p[hh][4 * g + 2] = e2;
        p[hh][4 * g + 3] = e3;
        s0 += e0;
        s1 += e1;
        s2 += e2;
        s3 += e3;
      }
    l_ += (s0 + s1) + (s2 + s3);
    // P^T B-frags via cvt_pk + permlane32_swap, then O^T += V^T * P^T
#pragma unroll
    for (int ks = 0; ks < 4; ++ks) {
      const int hh = ks >> 1, bq = (ks & 1) * 8;
      unsigned A0 = cvtpk(p[hh][bq + 0], p[hh][bq + 1]);
      unsigned A1 = cvtpk(p[hh][bq + 2], p[hh][bq + 3]);
      unsigned B0 = cvtpk(p[hh][bq + 4], p[hh][bq + 5]);
      unsigned B1 = cvtpk(p[hh][bq + 6], p[hh][bq + 7]);
      pswap(A0, B0);
      pswap(A1, B1);
      uint4v uu = {A0, A1, B0, B1};
      short8v pf = __builtin_bit_cast(short8v, uu);
#pragma unroll
      for (int dt = 0; dt < 2; ++dt) {
        int row = dt * 32 + l31;
        int sw = ((row ^ (row >> 3)) & 7) << 4;
        short8v vf =
            *(const short8v*)((const char*)lV[cur] + row * 128 + ((ks * 32 + L * 16) ^ sw));
        ot[dt] = __builtin_amdgcn_mfma_f32_32x32x16_bf16(vf, pf, ot[dt], 0, 0, 0);
      }
    }
    __syncthreads();  // staged next-tile done (vmcnt drain) + all reads of cur done
  }
  // epilogue: combine l across lane halves, O = O^T / l, write bf16
  l_ += __shfl_xor(l_, 32);
  float inv = 1.0f / l_;
  short* ob = O + ((size_t)(b * S_LEN + q)) * DMODEL + h * 64;
#pragma unroll
  for (int dt = 0; dt < 2; ++dt)
#pragma unroll
    for (int g = 0; g < 4; ++g) {
      int d0 = dt * 32 + 8 * g + 4 * L;
      uint2v w = {cvtpk(ot[dt][4 * g + 0] * inv, ot[dt][4 * g + 1] * inv),
                  cvtpk(ot[dt][4 * g + 2] * inv, ot[dt][4 * g + 3] * inv)};
      *(uint2v*)(ob + d0) = w;
    }
}

extern "C" void kernel_launch(void* const* d_in, const int* in_sizes, int n_in, void* d_out,
                              int out_size, void* d_ws, size_t ws_size, hipStream_t stream) {
  (void)in_sizes;
  (void)n_in;
  (void)out_size;
  (void)ws_size;
  const float* hs = (const float*)d_in[0];
  const float* mask = (const float*)d_in[1];
  const float* wq = (const float*)d_in[2];
  const float* wk = (const float*)d_in[3];
  const float* wv = (const float*)d_in[4];
  const float* wo = (const float*)d_in[5];
  const float* relb = (const float*)d_in[6];
  float* out = (float*)d_out;
  char* ws = (char*)d_ws;
  const size_t MB = 1024 * 1024;
  short* wT = (short*)(ws);              // [3072][1024] bf16
  short* wTo = (short*)(ws + 6 * MB);    // [1024][1024] bf16
  short* Ab = (short*)(ws + 8 * MB);     // [4096][1024] bf16 (hs); reused as Ob
  short* Qb = (short*)(ws + 16 * MB);    // [64][1024][64] bf16
  short* Kb = (short*)(ws + 24 * MB);
  short* Vb = (short*)(ws + 32 * MB);
  short* Vtb = (short*)(ws + 40 * MB);   // [64][64][1024] bf16
  short* B4 = (short*)(ws + 48 * MB);    // [16][2048][4] bf16 (256 KB)
  short* Msw = (short*)(ws + 49 * MB);   // [1024][1024] bf16 swizzled (2 MB)
  short* Ob = Ab;

  transpose4_k<<<dim3(32, 32, 4), dim3(32, 8), 0, stream>>>(wq, wk, wv, wo, wT, wTo);
  bias4_k<<<16 * 2048 / 256, 256, 0, stream>>>(relb, B4);
  masksw_k<<<1024 * 128 / 256, 256, 0, stream>>>(mask, Msw);
  cvt_k<<<4096 * 1024 / 8 / 256, 256, 0, stream>>>(hs, Ab);
  gemm2_k<0, 24, 32><<<768, 256, 0, stream>>>(Ab, wT, Qb, Kb, Vb, nullptr);
  vtrans_k<<<dim3(4, 64), 256, 0, stream>>>(Vb, Vtb);
  attn32_k<<<512, 256, 0, stream>>>(Qb, Kb, Vtb, Msw, B4, Ob);
  gemm2_k<1, 8, 32><<<256, 256, 0, stream>>>(Ob, wTo, nullptr, nullptr, nullptr, out);
}

// Round 7
// 180.718 us; speedup vs baseline: 1.1472x; 1.0830x over previous
//
#include <hip/hip_runtime.h>

typedef __attribute__((ext_vector_type(8))) short short8v;
typedef __attribute__((ext_vector_type(4))) short short4v;
typedef __attribute__((ext_vector_type(4))) float floatx4;
typedef __attribute__((ext_vector_type(16))) float f32x16;
typedef __attribute__((ext_vector_type(4))) unsigned uint4v;
typedef __attribute__((ext_vector_type(2))) unsigned uint2v;

#define S_LEN 1024
#define DMODEL 1024
#define NH 16
#define DK 64
#define NB_TAB 2047
#define L2E 1.4426950408889634f
#define FMAX_C 16.0f  // fixed softmax offset (log2 domain), folded into mask table

__device__ __forceinline__ short f2bf(float f) {
  unsigned u = __builtin_bit_cast(unsigned, f);
  u += 0x7fffu + ((u >> 16) & 1u);  // RNE
  return (short)(u >> 16);
}

__device__ __forceinline__ float b2f(short s) {
  return __builtin_bit_cast(float, ((unsigned)(unsigned short)s) << 16);
}

__device__ __forceinline__ unsigned cvtpk(float lo, float hi) {
  unsigned r;
  asm("v_cvt_pk_bf16_f32 %0, %1, %2" : "=v"(r) : "v"(lo), "v"(hi));
  return r;
}

__device__ __forceinline__ void pswap(unsigned& x, unsigned& y) {
  asm volatile("v_permlane32_swap_b32 %0, %1" : "+v"(x), "+v"(y));
}

__device__ __forceinline__ float exp2a(float x) {
  float r;
  asm("v_exp_f32 %0, %1" : "=v"(r) : "v"(x));
  return r;
}

__device__ __forceinline__ void load16(const void* g, void* l) {
  __builtin_amdgcn_global_load_lds((const __attribute__((address_space(1))) unsigned*)g,
                                   (__attribute__((address_space(3))) unsigned*)l, 16, 0, 0);
}

// ---------------- fused prep: transpose4 | cvt | bias4 | masksw ----------------
// grid: [0,4096) transpose, [4096,6144) cvt, [6144,6656) masksw, [6656,6784) bias4
__global__ __launch_bounds__(256) void prep_k(const float* __restrict__ hs,
                                              const float* __restrict__ mask,
                                              const float* __restrict__ wq,
                                              const float* __restrict__ wk,
                                              const float* __restrict__ wv,
                                              const float* __restrict__ wo,
                                              const float* __restrict__ relb,
                                              short* __restrict__ wT, short* __restrict__ wTo,
                                              short* __restrict__ Ab, short* __restrict__ Msw,
                                              short* __restrict__ B4) {
  __shared__ float t[32][33];
  int bid = blockIdx.x, tid = threadIdx.x;
  if (bid < 4096) {  // weight transpose, bf16
    int z = bid >> 10, tb = bid & 1023;
    const float* in = z == 0 ? wq : (z == 1 ? wk : (z == 2 ? wv : wo));
    short* out = z < 3 ? wT + (size_t)z * 1024 * 1024 : wTo;
    int tx = tid & 31, ty = tid >> 5;
    int bx = (tb & 31) * 32, by = (tb >> 5) * 32;
#pragma unroll
    for (int i = ty; i < 32; i += 8) t[i][tx] = in[(size_t)(by + i) * DMODEL + bx + tx];
    __syncthreads();
#pragma unroll
    for (int i = ty; i < 32; i += 8) out[(size_t)(bx + i) * DMODEL + by + tx] = f2bf(t[tx][i]);
  } else if (bid < 6144) {  // hs fp32 -> bf16
    size_t i = ((size_t)(bid - 4096) * 256 + tid) * 8;
    const floatx4* p = (const floatx4*)(hs + i);
    floatx4 a = p[0], b = p[1];
    short8v o;
#pragma unroll
    for (int j = 0; j < 4; ++j) {
      o[j] = f2bf(a[j]);
      o[4 + j] = f2bf(b[j]);
    }
    *(short8v*)(Ab + i) = o;
  } else if (bid < 6656) {  // mask -> bf16*(L2E) - FMAX_C, pre-swizzled
    int gid = (bid - 6144) * 256 + tid;
    int q = gid >> 7, kvg = gid & 127;
    int kv = kvg * 8;
    floatx4 m0 = *(const floatx4*)(mask + (size_t)q * 1024 + kv);
    floatx4 m1 = *(const floatx4*)(mask + (size_t)q * 1024 + kv + 4);
    unsigned u0 = cvtpk(m0[0] * L2E - FMAX_C, m0[1] * L2E - FMAX_C);
    unsigned u1 = cvtpk(m0[2] * L2E - FMAX_C, m0[3] * L2E - FMAX_C);
    unsigned u2 = cvtpk(m1[0] * L2E - FMAX_C, m1[1] * L2E - FMAX_C);
    unsigned u3 = cvtpk(m1[2] * L2E - FMAX_C, m1[3] * L2E - FMAX_C);
    uint4v uu;
    if (q & 8) {
      uu[0] = u2; uu[1] = u3; uu[2] = u0; uu[3] = u1;
    } else {
      uu[0] = u0; uu[1] = u1; uu[2] = u2; uu[3] = u3;
    }
    int seg = kvg >> 3, sslot = (kvg & 7) ^ (q & 7);
    *(uint4v*)(Msw + (size_t)q * 1024 + seg * 64 + sslot * 8) = uu;
  } else {  // 4-replicated bias table *L2E
    int gid = (bid - 6656) * 256 + tid;
    int h = gid >> 11, idx = gid & 2047;
    short4v o;
#pragma unroll
    for (int j = 0; j < 4; ++j) {
      int ri = idx + j;
      if (ri > 2046) ri = 2046;
      int rel = ri - 1023;
      int bucket = (rel > 0) ? 16 : 0;
      int r = rel < 0 ? -rel : rel;
      int bb;
      if (r < 8) {
        bb = r;
      } else {
        float lf = logf((float)r * 0.125f) * (8.0f / 2.772588722239781f);
        bb = 8 + (int)lf;
        if (bb > 15) bb = 15;
      }
      bucket += bb;
      o[j] = f2bf(relb[bucket * NH + h] * L2E);
    }
    *(short4v*)(B4 + (size_t)gid * 4) = o;
  }
}

// ---------------- QKV GEMM: BM=BN=128, BK=32, double-buffered, stage-early ----------------
// C = A[4096,1024] * BT[3072,1024]^T. Epilogue: Q(*L2E)/K -> [bh][s][64];
// V -> Vt[bh][d][s] pre-swizzled for attn staging (vtrans fused).
__global__ __launch_bounds__(256) void gemmQKV_k(const short* __restrict__ A,
                                                 const short* __restrict__ BT,
                                                 short* __restrict__ Qo, short* __restrict__ Ko,
                                                 short* __restrict__ Vt) {
  constexpr int K = DMODEL;
  __shared__ short lA[2][128 * 32];
  __shared__ short lB[2][128 * 32];
  int tid = threadIdx.x;
  int lane = tid & 63, wid = tid >> 6;
  int lane16 = lane & 15, kl = lane >> 4;
  // block swizzle: XCD chunk (96) then group-M(8); 768 blocks
  int bid = blockIdx.x;
  int lb = (bid & 7) * 96 + (bid >> 3);
  int g = lb / 192, r = lb % 192;
  int bm = (g * 8 + (r & 7)) * 128, bn = (r >> 3) * 128;
  int wm = (wid & 1) * 64, wn = (wid >> 1) * 64;
  floatx4 acc[4][4] = {};

  // staging: 2 insts/matrix, 64 rows each; row = it*64 + wid*16 + (lane>>2)
  const char* gA[2];
  const char* gB[2];
  int ldstS[2];
  {
    int slot = lane & 3;
#pragma unroll
    for (int it = 0; it < 2; ++it) {
      int row = it * 64 + wid * 16 + (lane >> 2);
      int ss = slot ^ ((row ^ (row >> 2)) & 3);
      gA[it] = (const char*)A + ((size_t)(bm + row) * K + ss * 8) * 2;
      gB[it] = (const char*)BT + ((size_t)(bn + row) * K + ss * 8) * 2;
      ldstS[it] = it * 4096 + wid * 1024;
    }
  }
  // prologue: stage tile 0
#pragma unroll
  for (int it = 0; it < 2; ++it) {
    load16(gA[it], (char*)lA[0] + ldstS[it]);
    load16(gB[it], (char*)lB[0] + ldstS[it]);
  }
  __syncthreads();

  for (int t = 0; t < 32; ++t) {
    int cur = t & 1;
    if (t < 31) {
      int kb = (t + 1) * 64;  // bytes along K (32 elems * 2B)
#pragma unroll
      for (int it = 0; it < 2; ++it) {
        load16(gA[it] + kb, (char*)lA[cur ^ 1] + ldstS[it]);
        load16(gB[it] + kb, (char*)lB[cur ^ 1] + ldstS[it]);
      }
    }
    short8v af[4], bf[4];
#pragma unroll
    for (int mt = 0; mt < 4; ++mt) {
      int row = wm + mt * 16 + lane16;
      int k2 = ((row ^ (row >> 2)) & 3) << 4;
      af[mt] = *(const short8v*)((char*)lA[cur] + row * 64 + ((kl * 16) ^ k2));
    }
#pragma unroll
    for (int nt = 0; nt < 4; ++nt) {
      int row = wn + nt * 16 + lane16;
      int k2 = ((row ^ (row >> 2)) & 3) << 4;
      bf[nt] = *(const short8v*)((char*)lB[cur] + row * 64 + ((kl * 16) ^ k2));
    }
#pragma unroll
    for (int mt = 0; mt < 4; ++mt)
#pragma unroll
      for (int nt = 0; nt < 4; ++nt)
        acc[mt][nt] =
            __builtin_amdgcn_mfma_f32_16x16x32_bf16(af[mt], bf[nt], acc[mt][nt], 0, 0, 0);
    __syncthreads();
  }

  int which = bn >> 10;
  int gcb = bn & 1023;
  if (which < 2) {  // Q or K -> [bh][s][64]
    short* dst = which == 0 ? Qo : Ko;
    float scl = which == 0 ? L2E : 1.0f;
#pragma unroll
    for (int mt = 0; mt < 4; ++mt)
#pragma unroll
      for (int nt = 0; nt < 4; ++nt)
#pragma unroll
        for (int r2 = 0; r2 < 4; ++r2) {
          int gr = bm + wm + mt * 16 + kl * 4 + r2;
          int gc = gcb + wn + nt * 16 + lane16;
          int hh = gc >> 6, d = gc & 63;
          int bb = gr >> 10, s = gr & 1023;
          dst[(size_t)((bb * 16 + hh) * 1024 + s) * 64 + d] = f2bf(acc[mt][nt][r2] * scl);
        }
  } else {  // V -> Vt[bh][d][s], 16B-group swizzled by key(d); 4 consecutive s = 8B store
#pragma unroll
    for (int mt = 0; mt < 4; ++mt)
#pragma unroll
      for (int nt = 0; nt < 4; ++nt) {
        int sb = bm + wm + mt * 16 + kl * 4;
        int gc = gcb + wn + nt * 16 + lane16;
        int hh = gc >> 6, d = gc & 63;
        int bb = sb >> 10, st = sb & 1023;
        int keyd = (d ^ (d >> 3)) & 7;
        size_t off = ((size_t)((bb * 16 + hh) * 64 + d)) * 1024 + (st & ~63) +
                     ((((st >> 3) & 7) ^ keyd) << 3) + (st & 7);
        short4v o;
#pragma unroll
        for (int r2 = 0; r2 < 4; ++r2) o[r2] = f2bf(acc[mt][nt][r2]);
        *(short4v*)(Vt + off) = o;
      }
  }
}

// ---------------- out-proj GEMM: BM=128, BN=64, BK=32, dbuf, grid 512 ----------------
__global__ __launch_bounds__(256) void gemmO_k(const short* __restrict__ A,
                                               const short* __restrict__ BT,
                                               float* __restrict__ Fo) {
  constexpr int K = DMODEL;
  __shared__ short lA[2][128 * 32];
  __shared__ short lB[2][64 * 32];
  int tid = threadIdx.x;
  int lane = tid & 63, wid = tid >> 6;
  int lane16 = lane & 15, kl = lane >> 4;
  int bid = blockIdx.x;
  int lb = (bid & 7) * 64 + (bid >> 3);  // 512 = 8*64
  int g = lb / 128, r = lb % 128;
  int bm = (g * 8 + (r & 7)) * 128, bn = (r >> 3) * 64;
  int wm = (wid & 1) * 64, wn = (wid >> 1) * 32;
  floatx4 acc[4][2] = {};

  const char* gA[2];
  const char* gB;
  int ldstS[2];
  {
    int slot = lane & 3;
#pragma unroll
    for (int it = 0; it < 2; ++it) {
      int row = it * 64 + wid * 16 + (lane >> 2);
      int ss = slot ^ ((row ^ (row >> 2)) & 3);
      gA[it] = (const char*)A + ((size_t)(bm + row) * K + ss * 8) * 2;
      ldstS[it] = it * 4096 + wid * 1024;
    }
    int row = wid * 16 + (lane >> 2);
    int ss = slot ^ ((row ^ (row >> 2)) & 3);
    gB = (const char*)BT + ((size_t)(bn + row) * K + ss * 8) * 2;
  }
#pragma unroll
  for (int it = 0; it < 2; ++it) load16(gA[it], (char*)lA[0] + ldstS[it]);
  load16(gB, (char*)lB[0] + ldstS[0]);
  __syncthreads();

  for (int t = 0; t < 32; ++t) {
    int cur = t & 1;
    if (t < 31) {
      int kb = (t + 1) * 64;
#pragma unroll
      for (int it = 0; it < 2; ++it) load16(gA[it] + kb, (char*)lA[cur ^ 1] + ldstS[it]);
      load16(gB + kb, (char*)lB[cur ^ 1] + ldstS[0]);
    }
    short8v af[4], bf[2];
#pragma unroll
    for (int mt = 0; mt < 4; ++mt) {
      int row = wm + mt * 16 + lane16;
      int k2 = ((row ^ (row >> 2)) & 3) << 4;
      af[mt] = *(const short8v*)((char*)lA[cur] + row * 64 + ((kl * 16) ^ k2));
    }
#pragma unroll
    for (int nt = 0; nt < 2; ++nt) {
      int row = wn + nt * 16 + lane16;
      int k2 = ((row ^ (row >> 2)) & 3) << 4;
      bf[nt] = *(const short8v*)((char*)lB[cur] + row * 64 + ((kl * 16) ^ k2));
    }
#pragma unroll
    for (int mt = 0; mt < 4; ++mt)
#pragma unroll
      for (int nt = 0; nt < 2; ++nt)
        acc[mt][nt] =
            __builtin_amdgcn_mfma_f32_16x16x32_bf16(af[mt], bf[nt], acc[mt][nt], 0, 0, 0);
    __syncthreads();
  }
#pragma unroll
  for (int mt = 0; mt < 4; ++mt)
#pragma unroll
    for (int nt = 0; nt < 2; ++nt)
#pragma unroll
      for (int r2 = 0; r2 < 4; ++r2) {
        int gr = bm + wm + mt * 16 + kl * 4 + r2;
        int gc = bn + wn + nt * 16 + lane16;
        Fo[(size_t)gr * DMODEL + gc] = acc[mt][nt][r2];
      }
}

// ---------------- flash attention (unchanged structure; V source now linear) ----------------
__global__ __launch_bounds__(256) void attn32_k(const short* __restrict__ Q,
                                                const short* __restrict__ Kg,
                                                const short* __restrict__ Vt,
                                                const short* __restrict__ Msw,
                                                const short* __restrict__ B4g,
                                                short* __restrict__ O) {
  __shared__ short lK[2][64 * 64];
  __shared__ short lV[2][64 * 64];
  __shared__ short lM[2][128 * 64];
  __shared__ short lB4[2048 * 4];
  int tid = threadIdx.x;
  int lane = tid & 63, wid = tid >> 6;
  int l31 = lane & 31, L = lane >> 5;
  int bid = blockIdx.x;
  int lb = (bid & 7) * 64 + (bid >> 3);
  int bh = lb >> 3, qt = lb & 7;
  int h = bh & 15, b = bh >> 4;
  int q = qt * 128 + wid * 32 + l31;
  int q_r = wid * 32 + l31;

  const char* gK[2];
  const char* gV[2];
  int ldst[2];
  {
    int slot = lane & 7;
#pragma unroll
    for (int i = 0; i < 2; ++i) {
      int row = i * 32 + wid * 8 + (lane >> 3);
      int ss = slot ^ ((row ^ (row >> 3)) & 7);
      gK[i] = (const char*)Kg + ((size_t)(bh * S_LEN + row) * DK + ss * 8) * 2;
      gV[i] = (const char*)Vt + ((size_t)(bh * DK + row) * S_LEN + slot * 8) * 2;  // pre-swz
      ldst[i] = (i * 32 + wid * 8) * 128;
    }
  }
  const char* gM[4];
  int ldstM[4];
#pragma unroll
  for (int c = 0; c < 4; ++c) {
    int row = c * 32 + wid * 8 + (lane >> 3);
    gM[c] = (const char*)Msw + ((size_t)(qt * 128 + row) * 1024) * 2 + (lane & 7) * 16;
    ldstM[c] = c * 4096 + wid * 1024;
  }
#pragma unroll
  for (int i = 0; i < 2; ++i) {
    load16(gK[i], (char*)lK[0] + ldst[i]);
    load16(gV[i], (char*)lV[0] + ldst[i]);
  }
#pragma unroll
  for (int c = 0; c < 4; ++c) load16(gM[c], (char*)lM[0] + ldstM[c]);
  {
    const short8v* src = (const short8v*)(B4g + (size_t)h * 8192);
    short8v* dst = (short8v*)lB4;
    for (int i = tid; i < 1024; i += 256) dst[i] = src[i];
  }
  const short8v* qp = (const short8v*)(Q + ((size_t)bh * S_LEN + q) * DK);
  short8v qf[4];
#pragma unroll
  for (int ds = 0; ds < 4; ++ds) qf[ds] = qp[ds * 2 + L];

  f32x16 ot[2] = {};
  float l_ = 0.0f;
  int swq = ((q_r & 7) << 4) | (q_r & 8);
  __syncthreads();

  for (int it = 0; it < 16; ++it) {
    int kv0 = it * 64;
    int cur = it & 1;
    if (it < 15) {
#pragma unroll
      for (int i = 0; i < 2; ++i) {
        load16(gK[i] + (size_t)(kv0 + 64) * 128, (char*)lK[cur ^ 1] + ldst[i]);
        load16(gV[i] + (size_t)(kv0 + 64) * 2, (char*)lV[cur ^ 1] + ldst[i]);
      }
#pragma unroll
      for (int c = 0; c < 4; ++c)
        load16(gM[c] + (size_t)(kv0 + 64) * 2, (char*)lM[cur ^ 1] + ldstM[c]);
    }
    short4v mb[2][4], bb[2][4];
#pragma unroll
    for (int hh = 0; hh < 2; ++hh)
#pragma unroll
      for (int g2 = 0; g2 < 4; ++g2) {
        mb[hh][g2] = *(const short4v*)((const char*)lM[cur] + q_r * 128 +
                                       ((hh * 64 + 16 * g2 + 8 * L) ^ swq));
        bb[hh][g2] =
            *(const short4v*)(lB4 + (size_t)(kv0 + hh * 32 + 8 * g2 + 4 * L - q + 1023) * 4);
      }
    f32x16 sA[2];
#pragma unroll
    for (int hh = 0; hh < 2; ++hh) {
      f32x16 acc = {};
#pragma unroll
      for (int ds = 0; ds < 4; ++ds) {
        int row = hh * 32 + l31;
        int sw = ((row ^ (row >> 3)) & 7) << 4;
        short8v kf =
            *(const short8v*)((const char*)lK[cur] + row * 128 + ((ds * 32 + L * 16) ^ sw));
        acc = __builtin_amdgcn_mfma_f32_32x32x16_bf16(kf, qf[ds], acc, 0, 0, 0);
      }
      sA[hh] = acc;
    }
    float p[2][16];
#pragma unroll
    for (int hh = 0; hh < 2; ++hh)
#pragma unroll
      for (int g2 = 0; g2 < 4; ++g2)
#pragma unroll
        for (int r3 = 0; r3 < 4; ++r3)
          p[hh][4 * g2 + r3] = sA[hh][4 * g2 + r3] + b2f(mb[hh][g2][r3]) + b2f(bb[hh][g2][r3]);
    float s0 = 0.0f, s1 = 0.0f, s2 = 0.0f, s3 = 0.0f;
#pragma unroll
    for (int hh = 0; hh < 2; ++hh)
#pragma unroll
      for (int g2 = 0; g2 < 4; ++g2) {
        float e0 = exp2a(p[hh][4 * g2 + 0]);
        float e1 = exp2a(p[hh][4 * g2 + 1]);
        float e2 = exp2a(p[hh][4 * g2 + 2]);
        float e3 = exp2a(p[hh][4 * g2 + 3]);
        p[hh][4 * g2 + 0] = e0;
        p[hh][4 * g2 + 1] = e1;
        p[hh][4 * g2 + 2] = e2;
        p[hh][4 * g2 + 3] = e3;
        s0 += e0;
        s1 += e1;
        s2 += e2;
        s3 += e3;
      }
    l_ += (s0 + s1) + (s2 + s3);
#pragma unroll
    for (int ks = 0; ks < 4; ++ks) {
      const int hh = ks >> 1, bq = (ks & 1) * 8;
      unsigned A0 = cvtpk(p[hh][bq + 0], p[hh][bq + 1]);
      unsigned A1 = cvtpk(p[hh][bq + 2], p[hh][bq + 3]);
      unsigned B0 = cvtpk(p[hh][bq + 4], p[hh][bq + 5]);
      unsigned B1 = cvtpk(p[hh][bq + 6], p[hh][bq + 7]);
      pswap(A0, B0);
      pswap(A1, B1);
      uint4v uu = {A0, A1, B0, B1};
      short8v pf = __builtin_bit_cast(short8v, uu);
#pragma unroll
      for (int dt = 0; dt < 2; ++dt) {
        int row = dt * 32 + l31;
        int sw = ((row ^ (row >> 3)) & 7) << 4;
        short8v vf =
            *(const short8v*)((const char*)lV[cur] + row * 128 + ((ks * 32 + L * 16) ^ sw));
        ot[dt] = __builtin_amdgcn_mfma_f32_32x32x16_bf16(vf, pf, ot[dt], 0, 0, 0);
      }
    }
    __syncthreads();
  }
  l_ += __shfl_xor(l_, 32);
  float inv = 1.0f / l_;
  short* ob = O + ((size_t)(b * S_LEN + q)) * DMODEL + h * 64;
#pragma unroll
  for (int dt = 0; dt < 2; ++dt)
#pragma unroll
    for (int g2 = 0; g2 < 4; ++g2) {
      int d0 = dt * 32 + 8 * g2 + 4 * L;
      uint2v w = {cvtpk(ot[dt][4 * g2 + 0] * inv, ot[dt][4 * g2 + 1] * inv),
                  cvtpk(ot[dt][4 * g2 + 2] * inv, ot[dt][4 * g2 + 3] * inv)};
      *(uint2v*)(ob + d0) = w;
    }
}

extern "C" void kernel_launch(void* const* d_in, const int* in_sizes, int n_in, void* d_out,
                              int out_size, void* d_ws, size_t ws_size, hipStream_t stream) {
  (void)in_sizes;
  (void)n_in;
  (void)out_size;
  (void)ws_size;
  const float* hs = (const float*)d_in[0];
  const float* mask = (const float*)d_in[1];
  const float* wq = (const float*)d_in[2];
  const float* wk = (const float*)d_in[3];
  const float* wv = (const float*)d_in[4];
  const float* wo = (const float*)d_in[5];
  const float* relb = (const float*)d_in[6];
  float* out = (float*)d_out;
  char* ws = (char*)d_ws;
  const size_t MB = 1024 * 1024;
  short* wT = (short*)(ws);              // [3072][1024] bf16
  short* wTo = (short*)(ws + 6 * MB);    // [1024][1024] bf16
  short* Ab = (short*)(ws + 8 * MB);     // [4096][1024] bf16 (hs); reused as Ob
  short* Qb = (short*)(ws + 16 * MB);    // [64][1024][64] bf16
  short* Kb = (short*)(ws + 24 * MB);
  short* Vtb = (short*)(ws + 32 * MB);   // [64][64][1024] bf16, pre-swizzled
  short* B4 = (short*)(ws + 48 * MB);    // [16][2048][4] bf16
  short* Msw = (short*)(ws + 49 * MB);   // [1024][1024] bf16 swizzled
  short* Ob = Ab;

  prep_k<<<6784, 256, 0, stream>>>(hs, mask, wq, wk, wv, wo, relb, wT, wTo, Ab, Msw, B4);
  gemmQKV_k<<<768, 256, 0, stream>>>(Ab, wT, Qb, Kb, Vtb);
  attn32_k<<<512, 256, 0, stream>>>(Qb, Kb, Vtb, Msw, B4, Ob);
  gemmO_k<<<512, 256, 0, stream>>>(Ob, wTo, out);
}

// Round 8
// 180.669 us; speedup vs baseline: 1.1476x; 1.0003x over previous
//
#include <hip/hip_runtime.h>

typedef __attribute__((ext_vector_type(8))) short short8v;
typedef __attribute__((ext_vector_type(4))) short short4v;
typedef __attribute__((ext_vector_type(4))) float floatx4;
typedef __attribute__((ext_vector_type(16))) float f32x16;
typedef __attribute__((ext_vector_type(4))) unsigned uint4v;
typedef __attribute__((ext_vector_type(2))) unsigned uint2v;

#define S_LEN 1024
#define DMODEL 1024
#define NH 16
#define DK 64
#define L2E 1.4426950408889634f
#define FMAX_C 16.0f  // fixed softmax offset (log2 domain), folded into mask table

__device__ __forceinline__ short f2bf(float f) {
  unsigned u = __builtin_bit_cast(unsigned, f);
  u += 0x7fffu + ((u >> 16) & 1u);  // RNE
  return (short)(u >> 16);
}

__device__ __forceinline__ float b2f(short s) {
  return __builtin_bit_cast(float, ((unsigned)(unsigned short)s) << 16);
}

__device__ __forceinline__ unsigned cvtpk(float lo, float hi) {
  unsigned r;
  asm("v_cvt_pk_bf16_f32 %0, %1, %2" : "=v"(r) : "v"(lo), "v"(hi));
  return r;
}

__device__ __forceinline__ void pswap(unsigned& x, unsigned& y) {
  asm volatile("v_permlane32_swap_b32 %0, %1" : "+v"(x), "+v"(y));
}

__device__ __forceinline__ float exp2a(float x) {
  float r;
  asm("v_exp_f32 %0, %1" : "=v"(r) : "v"(x));
  return r;
}

__device__ __forceinline__ void load16(const void* g, void* l) {
  __builtin_amdgcn_global_load_lds((const __attribute__((address_space(1))) unsigned*)g,
                                   (__attribute__((address_space(3))) unsigned*)l, 16, 0, 0);
}

#define BARRIER() asm volatile("s_barrier" ::: "memory")
#define VMCNT(n) asm volatile("s_waitcnt vmcnt(" #n ")" ::: "memory")

// ---------------- fused prep: transpose4 | cvt | bias4 | masksw ----------------
__global__ __launch_bounds__(256) void prep_k(const float* __restrict__ hs,
                                              const float* __restrict__ mask,
                                              const float* __restrict__ wq,
                                              const float* __restrict__ wk,
                                              const float* __restrict__ wv,
                                              const float* __restrict__ wo,
                                              const float* __restrict__ relb,
                                              short* __restrict__ wT, short* __restrict__ wTo,
                                              short* __restrict__ Ab, short* __restrict__ Msw,
                                              short* __restrict__ B4) {
  __shared__ float t[32][33];
  int bid = blockIdx.x, tid = threadIdx.x;
  if (bid < 4096) {  // weight transpose, bf16
    int z = bid >> 10, tb = bid & 1023;
    const float* in = z == 0 ? wq : (z == 1 ? wk : (z == 2 ? wv : wo));
    short* out = z < 3 ? wT + (size_t)z * 1024 * 1024 : wTo;
    int tx = tid & 31, ty = tid >> 5;
    int bx = (tb & 31) * 32, by = (tb >> 5) * 32;
#pragma unroll
    for (int i = ty; i < 32; i += 8) t[i][tx] = in[(size_t)(by + i) * DMODEL + bx + tx];
    __syncthreads();
#pragma unroll
    for (int i = ty; i < 32; i += 8) out[(size_t)(bx + i) * DMODEL + by + tx] = f2bf(t[tx][i]);
  } else if (bid < 6144) {  // hs fp32 -> bf16
    size_t i = ((size_t)(bid - 4096) * 256 + tid) * 8;
    const floatx4* p = (const floatx4*)(hs + i);
    floatx4 a = p[0], b = p[1];
    short8v o;
#pragma unroll
    for (int j = 0; j < 4; ++j) {
      o[j] = f2bf(a[j]);
      o[4 + j] = f2bf(b[j]);
    }
    *(short8v*)(Ab + i) = o;
  } else if (bid < 6656) {  // mask -> bf16*L2E - FMAX_C, pre-swizzled
    int gid = (bid - 6144) * 256 + tid;
    int q = gid >> 7, kvg = gid & 127;
    int kv = kvg * 8;
    floatx4 m0 = *(const floatx4*)(mask + (size_t)q * 1024 + kv);
    floatx4 m1 = *(const floatx4*)(mask + (size_t)q * 1024 + kv + 4);
    unsigned u0 = cvtpk(m0[0] * L2E - FMAX_C, m0[1] * L2E - FMAX_C);
    unsigned u1 = cvtpk(m0[2] * L2E - FMAX_C, m0[3] * L2E - FMAX_C);
    unsigned u2 = cvtpk(m1[0] * L2E - FMAX_C, m1[1] * L2E - FMAX_C);
    unsigned u3 = cvtpk(m1[2] * L2E - FMAX_C, m1[3] * L2E - FMAX_C);
    uint4v uu;
    if (q & 8) {
      uu[0] = u2; uu[1] = u3; uu[2] = u0; uu[3] = u1;
    } else {
      uu[0] = u0; uu[1] = u1; uu[2] = u2; uu[3] = u3;
    }
    int seg = kvg >> 3, sslot = (kvg & 7) ^ (q & 7);
    *(uint4v*)(Msw + (size_t)q * 1024 + seg * 64 + sslot * 8) = uu;
  } else {  // 4-replicated bias table *L2E
    int gid = (bid - 6656) * 256 + tid;
    int h = gid >> 11, idx = gid & 2047;
    short4v o;
#pragma unroll
    for (int j = 0; j < 4; ++j) {
      int ri = idx + j;
      if (ri > 2046) ri = 2046;
      int rel = ri - 1023;
      int bucket = (rel > 0) ? 16 : 0;
      int r = rel < 0 ? -rel : rel;
      int bb;
      if (r < 8) {
        bb = r;
      } else {
        float lf = logf((float)r * 0.125f) * (8.0f / 2.772588722239781f);
        bb = 8 + (int)lf;
        if (bb > 15) bb = 15;
      }
      bucket += bb;
      o[j] = f2bf(relb[bucket * NH + h] * L2E);
    }
    *(short4v*)(B4 + (size_t)gid * 4) = o;
  }
}

// ---------------- QKV GEMM: 128x128x32, 3-buf depth-2 pipeline, counted vmcnt ----------------
__global__ __launch_bounds__(256) void gemmQKV_k(const short* __restrict__ A,
                                                 const short* __restrict__ BT,
                                                 short* __restrict__ Qo, short* __restrict__ Ko,
                                                 short* __restrict__ Vt) {
  constexpr int K = DMODEL;
  __shared__ short lA[3 * 128 * 32];
  __shared__ short lB[3 * 128 * 32];
  int tid = threadIdx.x;
  int lane = tid & 63, wid = tid >> 6;
  int lane16 = lane & 15, kl = lane >> 4;
  int bid = blockIdx.x;
  int lb = (bid & 7) * 96 + (bid >> 3);
  int g = lb / 192, r = lb % 192;
  int bm = (g * 8 + (r & 7)) * 128, bn = (r >> 3) * 128;
  int wm = (wid & 1) * 64, wn = (wid >> 1) * 64;
  floatx4 acc[4][4] = {};

  const char* gA[2];
  const char* gB[2];
  int ldstS[2];
  {
    int slot = lane & 3;
#pragma unroll
    for (int it = 0; it < 2; ++it) {
      int row = it * 64 + wid * 16 + (lane >> 2);
      int ss = slot ^ ((row ^ (row >> 2)) & 3);
      gA[it] = (const char*)A + ((size_t)(bm + row) * K + ss * 8) * 2;
      gB[it] = (const char*)BT + ((size_t)(bn + row) * K + ss * 8) * 2;
      ldstS[it] = it * 4096 + wid * 1024;
    }
  }
  // rotating buffer base pointers (8 KB per buffer)
  char* a0 = (char*)lA;
  char* a1 = a0 + 8192;
  char* a2 = a1 + 8192;
  char* b0 = (char*)lB;
  char* b1 = b0 + 8192;
  char* b2 = b1 + 8192;
  // prologue: stage tiles 0 (buf0) and 1 (buf1)
#pragma unroll
  for (int it = 0; it < 2; ++it) {
    load16(gA[it], a0 + ldstS[it]);
    load16(gB[it], b0 + ldstS[it]);
  }
#pragma unroll
  for (int it = 0; it < 2; ++it) {
    load16(gA[it] + 64, a1 + ldstS[it]);
    load16(gB[it] + 64, b1 + ldstS[it]);
  }

  for (int t = 0; t < 32; ++t) {
    // wait: tile t's loads done (own wave); newest 4 (tile t+1) may stay in flight
    if (t < 31) {
      VMCNT(4);
    } else {
      VMCNT(0);
    }
    BARRIER();  // all waves: tile t landed; all reads of buf(t%3)-as-old done
    if (t < 30) {
      int kb = (t + 2) * 64;
#pragma unroll
      for (int it = 0; it < 2; ++it) {
        load16(gA[it] + kb, a2 + ldstS[it]);
        load16(gB[it] + kb, b2 + ldstS[it]);
      }
    }
    short8v af[4], bf[4];
#pragma unroll
    for (int mt = 0; mt < 4; ++mt) {
      int row = wm + mt * 16 + lane16;
      int k2 = ((row ^ (row >> 2)) & 3) << 4;
      af[mt] = *(const short8v*)(a0 + row * 64 + ((kl * 16) ^ k2));
    }
#pragma unroll
    for (int nt = 0; nt < 4; ++nt) {
      int row = wn + nt * 16 + lane16;
      int k2 = ((row ^ (row >> 2)) & 3) << 4;
      bf[nt] = *(const short8v*)(b0 + row * 64 + ((kl * 16) ^ k2));
    }
#pragma unroll
    for (int mt = 0; mt < 4; ++mt)
#pragma unroll
      for (int nt = 0; nt < 4; ++nt)
        acc[mt][nt] =
            __builtin_amdgcn_mfma_f32_16x16x32_bf16(af[mt], bf[nt], acc[mt][nt], 0, 0, 0);
    // rotate: consumed buffer becomes the stage-target two tiles ahead
    char* ta = a0; a0 = a1; a1 = a2; a2 = ta;
    char* tb = b0; b0 = b1; b1 = b2; b2 = tb;
  }

  int which = bn >> 10;
  int gcb = bn & 1023;
  if (which < 2) {  // Q or K -> [bh][s][64]
    short* dst = which == 0 ? Qo : Ko;
    float scl = which == 0 ? L2E : 1.0f;
#pragma unroll
    for (int mt = 0; mt < 4; ++mt)
#pragma unroll
      for (int nt = 0; nt < 4; ++nt)
#pragma unroll
        for (int r2 = 0; r2 < 4; ++r2) {
          int gr = bm + wm + mt * 16 + kl * 4 + r2;
          int gc = gcb + wn + nt * 16 + lane16;
          int hh = gc >> 6, d = gc & 63;
          int bb = gr >> 10, s = gr & 1023;
          dst[(size_t)((bb * 16 + hh) * 1024 + s) * 64 + d] = f2bf(acc[mt][nt][r2] * scl);
        }
  } else {  // V -> Vt[bh][d][s], pre-swizzled; 4 consecutive s = 8B store
#pragma unroll
    for (int mt = 0; mt < 4; ++mt)
#pragma unroll
      for (int nt = 0; nt < 4; ++nt) {
        int sb = bm + wm + mt * 16 + kl * 4;
        int gc = gcb + wn + nt * 16 + lane16;
        int hh = gc >> 6, d = gc & 63;
        int bb = sb >> 10, st = sb & 1023;
        int keyd = (d ^ (d >> 3)) & 7;
        size_t off = ((size_t)((bb * 16 + hh) * 64 + d)) * 1024 + (st & ~63) +
                     ((((st >> 3) & 7) ^ keyd) << 3) + (st & 7);
        short4v o;
#pragma unroll
        for (int r2 = 0; r2 < 4; ++r2) o[r2] = f2bf(acc[mt][nt][r2]);
        *(short4v*)(Vt + off) = o;
      }
  }
}

// ---------------- out-proj GEMM: 128x64x32, 3-buf depth-2 pipeline ----------------
__global__ __launch_bounds__(256) void gemmO_k(const short* __restrict__ A,
                                               const short* __restrict__ BT,
                                               float* __restrict__ Fo) {
  constexpr int K = DMODEL;
  __shared__ short lA[3 * 128 * 32];
  __shared__ short lB[3 * 64 * 32];
  int tid = threadIdx.x;
  int lane = tid & 63, wid = tid >> 6;
  int lane16 = lane & 15, kl = lane >> 4;
  int bid = blockIdx.x;
  int lb = (bid & 7) * 64 + (bid >> 3);
  int g = lb / 128, r = lb % 128;
  int bm = (g * 8 + (r & 7)) * 128, bn = (r >> 3) * 64;
  int wm = (wid & 1) * 64, wn = (wid >> 1) * 32;
  floatx4 acc[4][2] = {};

  const char* gA[2];
  const char* gB;
  int ldstS[2];
  {
    int slot = lane & 3;
#pragma unroll
    for (int it = 0; it < 2; ++it) {
      int row = it * 64 + wid * 16 + (lane >> 2);
      int ss = slot ^ ((row ^ (row >> 2)) & 3);
      gA[it] = (const char*)A + ((size_t)(bm + row) * K + ss * 8) * 2;
      ldstS[it] = it * 4096 + wid * 1024;
    }
    int row = wid * 16 + (lane >> 2);
    int ss = slot ^ ((row ^ (row >> 2)) & 3);
    gB = (const char*)BT + ((size_t)(bn + row) * K + ss * 8) * 2;
  }
  char* a0 = (char*)lA;
  char* a1 = a0 + 8192;
  char* a2 = a1 + 8192;
  char* b0 = (char*)lB;
  char* b1 = b0 + 4096;
  char* b2 = b1 + 4096;
#pragma unroll
  for (int it = 0; it < 2; ++it) load16(gA[it], a0 + ldstS[it]);
  load16(gB, b0 + ldstS[0]);
#pragma unroll
  for (int it = 0; it < 2; ++it) load16(gA[it] + 64, a1 + ldstS[it]);
  load16(gB + 64, b1 + ldstS[0]);

  for (int t = 0; t < 32; ++t) {
    if (t < 31) {
      VMCNT(3);
    } else {
      VMCNT(0);
    }
    BARRIER();
    if (t < 30) {
      int kb = (t + 2) * 64;
#pragma unroll
      for (int it = 0; it < 2; ++it) load16(gA[it] + kb, a2 + ldstS[it]);
      load16(gB + kb, b2 + ldstS[0]);
    }
    short8v af[4], bf[2];
#pragma unroll
    for (int mt = 0; mt < 4; ++mt) {
      int row = wm + mt * 16 + lane16;
      int k2 = ((row ^ (row >> 2)) & 3) << 4;
      af[mt] = *(const short8v*)(a0 + row * 64 + ((kl * 16) ^ k2));
    }
#pragma unroll
    for (int nt = 0; nt < 2; ++nt) {
      int row = wn + nt * 16 + lane16;
      int k2 = ((row ^ (row >> 2)) & 3) << 4;
      bf[nt] = *(const short8v*)(b0 + row * 64 + ((kl * 16) ^ k2));
    }
#pragma unroll
    for (int mt = 0; mt < 4; ++mt)
#pragma unroll
      for (int nt = 0; nt < 2; ++nt)
        acc[mt][nt] =
            __builtin_amdgcn_mfma_f32_16x16x32_bf16(af[mt], bf[nt], acc[mt][nt], 0, 0, 0);
    char* ta = a0; a0 = a1; a1 = a2; a2 = ta;
    char* tb = b0; b0 = b1; b1 = b2; b2 = tb;
  }
#pragma unroll
  for (int mt = 0; mt < 4; ++mt)
#pragma unroll
    for (int nt = 0; nt < 2; ++nt)
#pragma unroll
      for (int r2 = 0; r2 < 4; ++r2) {
        int gr = bm + wm + mt * 16 + kl * 4 + r2;
        int gc = bn + wn + nt * 16 + lane16;
        Fo[(size_t)gr * DMODEL + gc] = acc[mt][nt][r2];
      }
}

// ---------------- flash attention (r7 structure + T5 setprio) ----------------
__global__ __launch_bounds__(256) void attn32_k(const short* __restrict__ Q,
                                                const short* __restrict__ Kg,
                                                const short* __restrict__ Vt,
                                                const short* __restrict__ Msw,
                                                const short* __restrict__ B4g,
                                                short* __restrict__ O) {
  __shared__ short lK[2][64 * 64];
  __shared__ short lV[2][64 * 64];
  __shared__ short lM[2][128 * 64];
  __shared__ short lB4[2048 * 4];
  int tid = threadIdx.x;
  int lane = tid & 63, wid = tid >> 6;
  int l31 = lane & 31, L = lane >> 5;
  int bid = blockIdx.x;
  int lb = (bid & 7) * 64 + (bid >> 3);
  int bh = lb >> 3, qt = lb & 7;
  int h = bh & 15, b = bh >> 4;
  int q = qt * 128 + wid * 32 + l31;
  int q_r = wid * 32 + l31;

  const char* gK[2];
  const char* gV[2];
  int ldst[2];
  {
    int slot = lane & 7;
#pragma unroll
    for (int i = 0; i < 2; ++i) {
      int row = i * 32 + wid * 8 + (lane >> 3);
      int ss = slot ^ ((row ^ (row >> 3)) & 7);
      gK[i] = (const char*)Kg + ((size_t)(bh * S_LEN + row) * DK + ss * 8) * 2;
      gV[i] = (const char*)Vt + ((size_t)(bh * DK + row) * S_LEN + slot * 8) * 2;  // pre-swz
      ldst[i] = (i * 32 + wid * 8) * 128;
    }
  }
  const char* gM[4];
  int ldstM[4];
#pragma unroll
  for (int c = 0; c < 4; ++c) {
    int row = c * 32 + wid * 8 + (lane >> 3);
    gM[c] = (const char*)Msw + ((size_t)(qt * 128 + row) * 1024) * 2 + (lane & 7) * 16;
    ldstM[c] = c * 4096 + wid * 1024;
  }
#pragma unroll
  for (int i = 0; i < 2; ++i) {
    load16(gK[i], (char*)lK[0] + ldst[i]);
    load16(gV[i], (char*)lV[0] + ldst[i]);
  }
#pragma unroll
  for (int c = 0; c < 4; ++c) load16(gM[c], (char*)lM[0] + ldstM[c]);
  {
    const short8v* src = (const short8v*)(B4g + (size_t)h * 8192);
    short8v* dst = (short8v*)lB4;
    for (int i = tid; i < 1024; i += 256) dst[i] = src[i];
  }
  const short8v* qp = (const short8v*)(Q + ((size_t)bh * S_LEN + q) * DK);
  short8v qf[4];
#pragma unroll
  for (int ds = 0; ds < 4; ++ds) qf[ds] = qp[ds * 2 + L];

  f32x16 ot[2] = {};
  float l_ = 0.0f;
  int swq = ((q_r & 7) << 4) | (q_r & 8);
  __syncthreads();

  for (int it = 0; it < 16; ++it) {
    int kv0 = it * 64;
    int cur = it & 1;
    if (it < 15) {
#pragma unroll
      for (int i = 0; i < 2; ++i) {
        load16(gK[i] + (size_t)(kv0 + 64) * 128, (char*)lK[cur ^ 1] + ldst[i]);
        load16(gV[i] + (size_t)(kv0 + 64) * 2, (char*)lV[cur ^ 1] + ldst[i]);
      }
#pragma unroll
      for (int c = 0; c < 4; ++c)
        load16(gM[c] + (size_t)(kv0 + 64) * 2, (char*)lM[cur ^ 1] + ldstM[c]);
    }
    short4v mb[2][4], bb[2][4];
#pragma unroll
    for (int hh = 0; hh < 2; ++hh)
#pragma unroll
      for (int g2 = 0; g2 < 4; ++g2) {
        mb[hh][g2] = *(const short4v*)((const char*)lM[cur] + q_r * 128 +
                                       ((hh * 64 + 16 * g2 + 8 * L) ^ swq));
        bb[hh][g2] =
            *(const short4v*)(lB4 + (size_t)(kv0 + hh * 32 + 8 * g2 + 4 * L - q + 1023) * 4);
      }
    f32x16 sA[2];
    __builtin_amdgcn_s_setprio(1);
#pragma unroll
    for (int hh = 0; hh < 2; ++hh) {
      f32x16 acc = {};
#pragma unroll
      for (int ds = 0; ds < 4; ++ds) {
        int row = hh * 32 + l31;
        int sw = ((row ^ (row >> 3)) & 7) << 4;
        short8v kf =
            *(const short8v*)((const char*)lK[cur] + row * 128 + ((ds * 32 + L * 16) ^ sw));
        acc = __builtin_amdgcn_mfma_f32_32x32x16_bf16(kf, qf[ds], acc, 0, 0, 0);
      }
      sA[hh] = acc;
    }
    __builtin_amdgcn_s_setprio(0);
    float p[2][16];
#pragma unroll
    for (int hh = 0; hh < 2; ++hh)
#pragma unroll
      for (int g2 = 0; g2 < 4; ++g2)
#pragma unroll
        for (int r3 = 0; r3 < 4; ++r3)
          p[hh][4 * g2 + r3] = sA[hh][4 * g2 + r3] + b2f(mb[hh][g2][r3]) + b2f(bb[hh][g2][r3]);
    float s0 = 0.0f, s1 = 0.0f, s2 = 0.0f, s3 = 0.0f;
#pragma unroll
    for (int hh = 0; hh < 2; ++hh)
#pragma unroll
      for (int g2 = 0; g2 < 4; ++g2) {
        float e0 = exp2a(p[hh][4 * g2 + 0]);
        float e1 = exp2a(p[hh][4 * g2 + 1]);
        float e2 = exp2a(p[hh][4 * g2 + 2]);
        float e3 = exp2a(p[hh][4 * g2 + 3]);
        p[hh][4 * g2 + 0] = e0;
        p[hh][4 * g2 + 1] = e1;
        p[hh][4 * g2 + 2] = e2;
        p[hh][4 * g2 + 3] = e3;
        s0 += e0;
        s1 += e1;
        s2 += e2;
        s3 += e3;
      }
    l_ += (s0 + s1) + (s2 + s3);
    __builtin_amdgcn_s_setprio(1);
#pragma unroll
    for (int ks = 0; ks < 4; ++ks) {
      const int hh = ks >> 1, bq = (ks & 1) * 8;
      unsigned A0 = cvtpk(p[hh][bq + 0], p[hh][bq + 1]);
      unsigned A1 = cvtpk(p[hh][bq + 2], p[hh][bq + 3]);
      unsigned B0 = cvtpk(p[hh][bq + 4], p[hh][bq + 5]);
      unsigned B1 = cvtpk(p[hh][bq + 6], p[hh][bq + 7]);
      pswap(A0, B0);
      pswap(A1, B1);
      uint4v uu = {A0, A1, B0, B1};
      short8v pf = __builtin_bit_cast(short8v, uu);
#pragma unroll
      for (int dt = 0; dt < 2; ++dt) {
        int row = dt * 32 + l31;
        int sw = ((row ^ (row >> 3)) & 7) << 4;
        short8v vf =
            *(const short8v*)((const char*)lV[cur] + row * 128 + ((ks * 32 + L * 16) ^ sw));
        ot[dt] = __builtin_amdgcn_mfma_f32_32x32x16_bf16(vf, pf, ot[dt], 0, 0, 0);
      }
    }
    __builtin_amdgcn_s_setprio(0);
    __syncthreads();
  }
  l_ += __shfl_xor(l_, 32);
  float inv = 1.0f / l_;
  short* ob = O + ((size_t)(b * S_LEN + q)) * DMODEL + h * 64;
#pragma unroll
  for (int dt = 0; dt < 2; ++dt)
#pragma unroll
    for (int g2 = 0; g2 < 4; ++g2) {
      int d0 = dt * 32 + 8 * g2 + 4 * L;
      uint2v w = {cvtpk(ot[dt][4 * g2 + 0] * inv, ot[dt][4 * g2 + 1] * inv),
                  cvtpk(ot[dt][4 * g2 + 2] * inv, ot[dt][4 * g2 + 3] * inv)};
      *(uint2v*)(ob + d0) = w;
    }
}

extern "C" void kernel_launch(void* const* d_in, const int* in_sizes, int n_in, void* d_out,
                              int out_size, void* d_ws, size_t ws_size, hipStream_t stream) {
  (void)in_sizes;
  (void)n_in;
  (void)out_size;
  (void)ws_size;
  const float* hs = (const float*)d_in[0];
  const float* mask = (const float*)d_in[1];
  const float* wq = (const float*)d_in[2];
  const float* wk = (const float*)d_in[3];
  const float* wv = (const float*)d_in[4];
  const float* wo = (const float*)d_in[5];
  const float* relb = (const float*)d_in[6];
  float* out = (float*)d_out;
  char* ws = (char*)d_ws;
  const size_t MB = 1024 * 1024;
  short* wT = (short*)(ws);              // [3072][1024] bf16
  short* wTo = (short*)(ws + 6 * MB);    // [1024][1024] bf16
  short* Ab = (short*)(ws + 8 * MB);     // [4096][1024] bf16 (hs); reused as Ob
  short* Qb = (short*)(ws + 16 * MB);    // [64][1024][64] bf16
  short* Kb = (short*)(ws + 24 * MB);
  short* Vtb = (short*)(ws + 32 * MB);   // [64][64][1024] bf16, pre-swizzled
  short* B4 = (short*)(ws + 48 * MB);    // [16][2048][4] bf16
  short* Msw = (short*)(ws + 49 * MB);   // [1024][1024] bf16 swizzled
  short* Ob = Ab;

  prep_k<<<6784, 256, 0, stream>>>(hs, mask, wq, wk, wv, wo, relb, wT, wTo, Ab, Msw, B4);
  gemmQKV_k<<<768, 256, 0, stream>>>(Ab, wT, Qb, Kb, Vtb);
  attn32_k<<<512, 256, 0, stream>>>(Qb, Kb, Vtb, Msw, B4, Ob);
  gemmO_k<<<512, 256, 0, stream>>>(Ob, wTo, out);
}